// Round 7
// baseline (94.448 us; speedup 1.0000x reference)
//
#include <hip/hip_runtime.h>
#include <math.h>

// ---- problem constants (fixed by reference) ----
#define T_TOK 1024
#define H_DIM 768
#define I_DIM 3072
#define E_NUM 8
#define BM    128
#define BN    64
#define BK    64
#define MSLOTS 16    // max m-tiles at BM=128: 8 + 7 = 15
#define KSPLIT2 4    // FFN2 split-K factor

typedef __attribute__((ext_vector_type(8))) short  short8;   // 8 bf16
typedef __attribute__((ext_vector_type(4))) float  f32x4;

__device__ __forceinline__ unsigned short f2bf(float f) {
  union { float f; unsigned u; } a; a.f = f;
  unsigned r = a.u + 0x7FFFu + ((a.u >> 16) & 1u);  // RTNE
  return (unsigned short)(r >> 16);
}
__device__ __forceinline__ float gelu_exact(float x) {
  return 0.5f * x * (1.0f + erff(x * 0.70710678118654752f));
}
// XOR swizzle: row-major [row][BK] bf16 tile -> conflict-free ds_read_b128 (G4).
__device__ __forceinline__ int swz(int row, int k) {
  return row * BK + (k ^ ((row & 7) << 3));
}
// async global->LDS, 16B per lane. LDS dest = wave-uniform base + lane*16.
__device__ __forceinline__ void gll16(const void* g, void* l) {
  __builtin_amdgcn_global_load_lds(
      (const __attribute__((address_space(1))) void*)g,
      (__attribute__((address_space(3))) void*)l, 16, 0, 0);
}

// ---- kernel 1: deterministic expert routing (ballot rank) + tile list ----
__global__ __launch_bounds__(1024) void route_kernel(
    const int* __restrict__ eidx, int* __restrict__ perm,
    int* __restrict__ tile_e, int* __restrict__ tile_row,
    int* __restrict__ tile_len, int* __restrict__ ntiles) {
  __shared__ int wcnt[16][E_NUM];
  __shared__ int wpre[16][E_NUM];
  __shared__ int offsh[E_NUM + 1];
  const int t = threadIdx.x;        // 1024
  const int lane = t & 63, wave = t >> 6;
  const int e = eidx[t];
  unsigned long long myMask = 0;
#pragma unroll
  for (int ee = 0; ee < E_NUM; ++ee) {
    unsigned long long m = __ballot(e == ee);
    if (ee == e) myMask = m;
    if (lane == 0) wcnt[wave][ee] = __popcll(m);
  }
  const int rank = __popcll(myMask & ((1ull << lane) - 1ull));
  __syncthreads();
  if (t < 16 * E_NUM) {
    const int w = t >> 3, ee = t & 7;
    int p = 0;
    for (int w2 = 0; w2 < w; ++w2) p += wcnt[w2][ee];
    wpre[w][ee] = p;
  }
  __syncthreads();
  if (t <= E_NUM) {
    int off = 0;
    for (int ee = 0; ee < t; ++ee) off += wpre[15][ee] + wcnt[15][ee];
    offsh[t] = off;
  }
  __syncthreads();
  perm[offsh[e] + wpre[wave][e] + rank] = t;
  if (t == 0) {
    int n = 0;
    for (int ee = 0; ee < E_NUM; ++ee)
      for (int r = offsh[ee]; r < offsh[ee + 1]; r += BM) {
        tile_e[n] = ee; tile_row[n] = r;
        tile_len[n] = min(offsh[ee + 1] - r, BM); ++n;
      }
    *ntiles = n;
    for (int i = n; i < MSLOTS; ++i) { tile_e[i] = 0; tile_row[i] = 0; tile_len[i] = 0; }
  }
}

// ---- kernel 2: gather x into perm order, f32 -> bf16 ----
__global__ void gather_kernel(const float* __restrict__ x,
                              const int* __restrict__ perm,
                              unsigned short* __restrict__ xg) {
  const int idx = blockIdx.x * 256 + threadIdx.x;
  if (idx >= T_TOK * (H_DIM / 8)) return;
  const int p = idx / (H_DIM / 8);
  const int c = (idx % (H_DIM / 8)) * 8;
  const int t = perm[p];
  const float* src = x + (size_t)t * H_DIM + c;
  const float4 v0 = *(const float4*)(src);
  const float4 v1 = *(const float4*)(src + 4);
  short8 o;
  o[0] = (short)f2bf(v0.x); o[1] = (short)f2bf(v0.y);
  o[2] = (short)f2bf(v0.z); o[3] = (short)f2bf(v0.w);
  o[4] = (short)f2bf(v1.x); o[5] = (short)f2bf(v1.y);
  o[6] = (short)f2bf(v1.z); o[7] = (short)f2bf(v1.w);
  *(short8*)(xg + (size_t)p * H_DIM + c) = o;
}

// ---- grouped GEMM, BM=128 x BN=64, 8 waves (4x2, 32x32 each), dbuf LDS ----
// Counted-vmcnt pipeline (T4): B weights 2 phases deep, never drained to 0
// in-loop. A via global_load_lds (pre-swizzled source, linear dest, m173).
// B: 2x dwordx4/thread, f32->bf16 in regs, 8x ds_write_b16 (2-way, free).
template <int N_FULL, int K_FULL, int KLOOP, bool IS_FFN1>
__global__ __launch_bounds__(512, 6) void moe_gemm(
    const unsigned short* __restrict__ A,   // [T_TOK][K_FULL] bf16 (perm order)
    const float* __restrict__ W,            // [E][K_FULL][N_FULL] f32
    const float* __restrict__ bias,         // [E][N_FULL] (FFN1 only)
    const int* __restrict__ tile_e, const int* __restrict__ tile_row,
    const int* __restrict__ tile_len, const int* __restrict__ ntiles,
    unsigned short* __restrict__ out_bf,    // FFN1 out
    float* __restrict__ part) {             // FFN2 partials [KSPLIT2][T_TOK][N_FULL]
  constexpr int KT = KLOOP / BK;            // 12 (even)
  const int tid  = threadIdx.x;
  const int slot = blockIdx.y;
  if (slot >= *ntiles) return;
  const int e    = tile_e[slot];
  const int row0 = tile_row[slot];
  const int len  = tile_len[slot];
  const int n0   = blockIdx.x * BN;
  const int kbase = blockIdx.z * KLOOP;
  const float* We = W + (size_t)e * K_FULL * N_FULL;

  __shared__ unsigned short As[2][BM * BK];   // 2 x 16 KB, linear chunk order
  __shared__ unsigned short Bs[2][BN * BK];   // 2 x  8 KB, [n][k] swizzled

  const int lane = tid & 63;
  const int wave = tid >> 6;
  const int wm = wave >> 1, wn = wave & 1;    // 4x2 waves: 32 rows x 32 cols each
  const int lr = lane & 15;
  const int lk = (lane >> 4) * 8;

  // A gll addressing: linear LDS chunk c holds global (r, kc ^ xor(r)) so the
  // swizzled ds_read below sees the standard layout (pre-swizzled source).
  const unsigned short* agsrc[2];
  int aoff[2];
#pragma unroll
  for (int i = 0; i < 2; ++i) {
    const int c = tid + i * 512;
    const int r = c >> 3, kc = (c & 7) << 3;
    int grow = row0 + r; grow = grow < T_TOK ? grow : (T_TOK - 1);
    agsrc[i] = A + (size_t)grow * K_FULL + kbase + (kc ^ ((r & 7) << 3));
    aoff[i]  = ((tid & ~63) + i * 512) * 8;   // wave-uniform 16B-chunk base
  }
  // B staging: thread owns (k = lane, col-groups g*4 and g*4+32), g = wave.
  const int kk = tid & 63, g = tid >> 6;
  const float* wpB = We + (size_t)(kbase + kk) * N_FULL + n0 + g * 4;

  f32x4 acc[2][2] = {};
  float X[8], Y[8];

  auto issueA = [&](int kt, int buf) {
#pragma unroll
    for (int i = 0; i < 2; ++i)
      gll16(agsrc[i] + kt * BK, &As[buf][aoff[i]]);
  };
  auto loadB = [&](int kt, float* d) {
    const float4 v0 = *(const float4*)(wpB + (size_t)kt * BK * N_FULL);
    const float4 v1 = *(const float4*)(wpB + (size_t)kt * BK * N_FULL + 32);
    d[0] = v0.x; d[1] = v0.y; d[2] = v0.z; d[3] = v0.w;
    d[4] = v1.x; d[5] = v1.y; d[6] = v1.z; d[7] = v1.w;
  };
  auto writeB = [&](int buf, const float* d) {
#pragma unroll
    for (int j = 0; j < 4; ++j) {
      Bs[buf][swz(g * 4 + j, kk)]      = f2bf(d[j]);      // 64 lanes span 128B
      Bs[buf][swz(g * 4 + 32 + j, kk)] = f2bf(d[4 + j]);  // -> 2/bank, free
    }
  };
  auto mfma_tile = [&](int buf) {
#pragma unroll
    for (int ks = 0; ks < 2; ++ks) {
      const int kp = ks * 32 + lk;
      short8 af[2], bfr[2];
#pragma unroll
      for (int m = 0; m < 2; ++m)
        af[m] = *(const short8*)(&As[buf][swz(wm * 32 + m * 16 + lr, kp)]);
#pragma unroll
      for (int n = 0; n < 2; ++n)
        bfr[n] = *(const short8*)(&Bs[buf][swz(wn * 32 + n * 16 + lr, kp)]);
#pragma unroll
      for (int m = 0; m < 2; ++m)
#pragma unroll
        for (int n = 0; n < 2; ++n)
          acc[m][n] = __builtin_amdgcn_mfma_f32_16x16x32_bf16(af[m], bfr[n], acc[m][n], 0, 0, 0);
    }
  };
  // phase t: entry outstanding = {gll(t), B(t+1)} -> vmcnt(2) drains gll(t),
  // keeps B(t+1) in flight. Last phase drains all (vmcnt 0).
  auto phase = [&](int t, int buf, float* setCur, bool nextA, bool nextB, bool drain) {
    if (drain) asm volatile("s_waitcnt vmcnt(0)" ::: "memory");
    else       asm volatile("s_waitcnt vmcnt(2)" ::: "memory");
    writeB(buf, setCur);
    asm volatile("s_waitcnt lgkmcnt(0)" ::: "memory");
    __builtin_amdgcn_s_barrier();
    __builtin_amdgcn_sched_barrier(0);
    if (nextA) issueA(t + 1, buf ^ 1);
    __builtin_amdgcn_sched_barrier(0);
    if (nextB) loadB(t + 2, setCur);     // reuses the set just written to LDS
    mfma_tile(buf);
  };

  loadB(0, X);
  issueA(0, 0);
  __builtin_amdgcn_sched_barrier(0);
  loadB(1, Y);                            // must be the newest 2 VMEM ops
#pragma unroll 1
  for (int t = 0; t < KT - 2; t += 2) {
    phase(t,     0, X, true, true, false);
    phase(t + 1, 1, Y, true, true, false);
  }
  phase(KT - 2, 0, X, true,  false, false);
  phase(KT - 1, 1, Y, false, false, true);

  // epilogue: C/D layout col=lane&15, row=(lane>>4)*4+j  [verified m89]
#pragma unroll
  for (int n = 0; n < 2; ++n) {
    const int gc = n0 + wn * 32 + n * 16 + lr;
    float bv = 0.f;
    if constexpr (IS_FFN1) bv = bias[(size_t)e * N_FULL + gc];
#pragma unroll
    for (int m = 0; m < 2; ++m) {
      const int rbase = wm * 32 + m * 16 + (lane >> 4) * 4;
#pragma unroll
      for (int j = 0; j < 4; ++j) {
        const int rl = rbase + j;
        if (rl < len) {
          if constexpr (IS_FFN1) {
            out_bf[(size_t)(row0 + rl) * N_FULL + gc] = f2bf(gelu_exact(acc[m][n][j] + bv));
          } else {
            part[((size_t)blockIdx.z * T_TOK + row0 + rl) * N_FULL + gc] = acc[m][n][j];
          }
        }
      }
    }
  }
}

// ---- kernel 5: split-K sum + bias2 + residual + LayerNorm ----
__global__ void ln_kernel(const float* __restrict__ part,
                          const float* __restrict__ x,
                          const int* __restrict__ perm,
                          const int* __restrict__ eidx,
                          const float* __restrict__ b2,
                          const float* __restrict__ gamma,
                          const float* __restrict__ beta,
                          float* __restrict__ out) {
  const int p = blockIdx.x;
  const int tid = threadIdx.x;  // 256
  const int t = perm[p];
  const int e = eidx[t];
  float v[3], s = 0.f, ss = 0.f;
#pragma unroll
  for (int i = 0; i < 3; ++i) {
    const int c = tid + i * 256;
    float a = x[(size_t)t * H_DIM + c] + b2[(size_t)e * H_DIM + c];
#pragma unroll
    for (int s4 = 0; s4 < KSPLIT2; ++s4)
      a += part[((size_t)s4 * T_TOK + p) * H_DIM + c];
    v[i] = a; s += a; ss += a * a;
  }
#pragma unroll
  for (int o = 32; o; o >>= 1) { s += __shfl_down(s, o); ss += __shfl_down(ss, o); }
  __shared__ float ps[4], pss[4];
  __shared__ float mu_s, ir_s;
  const int w = tid >> 6;
  if ((tid & 63) == 0) { ps[w] = s; pss[w] = ss; }
  __syncthreads();
  if (tid == 0) {
    const float S = ps[0] + ps[1] + ps[2] + ps[3];
    const float SS = pss[0] + pss[1] + pss[2] + pss[3];
    const float mu = S * (1.0f / H_DIM);
    const float var = SS * (1.0f / H_DIM) - mu * mu;
    mu_s = mu; ir_s = rsqrtf(var + 1e-12f);
  }
  __syncthreads();
  const float mu = mu_s, ir = ir_s;
#pragma unroll
  for (int i = 0; i < 3; ++i) {
    const int c = tid + i * 256;
    out[(size_t)t * H_DIM + c] = (v[i] - mu) * ir * gamma[c] + beta[c];
  }
}

extern "C" void kernel_launch(void* const* d_in, const int* in_sizes, int n_in,
                              void* d_out, int out_size, void* d_ws, size_t ws_size,
                              hipStream_t stream) {
  const float* x     = (const float*)d_in[0];
  const int*   eidx  = (const int*)d_in[1];
  const float* W1    = (const float*)d_in[2];
  const float* b1    = (const float*)d_in[3];
  const float* W2    = (const float*)d_in[4];
  const float* b2    = (const float*)d_in[5];
  const float* gamma = (const float*)d_in[6];
  const float* beta  = (const float*)d_in[7];
  float* out = (float*)d_out;

  char* ws = (char*)d_ws;
  int* perm     = (int*)(ws);
  int* tile_e   = (int*)(ws + 4096);
  int* tile_row = (int*)(ws + 4352);
  int* tile_len = (int*)(ws + 4608);
  int* ntiles   = (int*)(ws + 4864);
  size_t off = 8192;
  unsigned short* xg = (unsigned short*)(ws + off);  off += (size_t)2 * T_TOK * H_DIM;   // 1.5 MB
  unsigned short* inter = (unsigned short*)(ws + off); off += (size_t)2 * T_TOK * I_DIM; // 6 MB
  float* part = (float*)(ws + off);                                                      // 12 MB

  route_kernel<<<1, T_TOK, 0, stream>>>(eidx, perm, tile_e, tile_row, tile_len, ntiles);
  gather_kernel<<<(T_TOK * (H_DIM / 8) + 255) / 256, 256, 0, stream>>>(x, perm, xg);
  // FFN1: N=3072, K=768. grid 48 x 16
  moe_gemm<I_DIM, H_DIM, H_DIM, true>
      <<<dim3(I_DIM / BN, MSLOTS, 1), 512, 0, stream>>>(
      xg, W1, b1, tile_e, tile_row, tile_len, ntiles, inter, nullptr);
  // FFN2: N=768, K=3072 split 4 x 768. grid 12 x 16 x 4
  moe_gemm<H_DIM, I_DIM, I_DIM / KSPLIT2, false>
      <<<dim3(H_DIM / BN, MSLOTS, KSPLIT2), 512, 0, stream>>>(
      inter, W2, nullptr, tile_e, tile_row, tile_len, ntiles, nullptr, part);
  ln_kernel<<<T_TOK, 256, 0, stream>>>(part, x, perm, eidx, b2, gamma, beta, out);
  (void)in_sizes; (void)n_in; (void)out_size; (void)ws_size;
}

// Round 8
// 75.996 us; speedup vs baseline: 1.2428x; 1.2428x over previous
//
#include <hip/hip_runtime.h>
#include <math.h>

// ---- problem constants (fixed by reference) ----
#define T_TOK 1024
#define H_DIM 768
#define I_DIM 3072
#define E_NUM 8
#define BM    128
#define BN    64
#define BK    64
#define MSLOTS 16    // max m-tiles at BM=128: 8 + 7 = 15
#define KSPLIT2 4    // FFN2 split-K factor

typedef __attribute__((ext_vector_type(8))) short  short8;   // 8 bf16
typedef __attribute__((ext_vector_type(4))) float  f32x4;

__device__ __forceinline__ unsigned short f2bf(float f) {
  union { float f; unsigned u; } a; a.f = f;
  unsigned r = a.u + 0x7FFFu + ((a.u >> 16) & 1u);  // RTNE
  return (unsigned short)(r >> 16);
}
__device__ __forceinline__ float gelu_exact(float x) {
  return 0.5f * x * (1.0f + erff(x * 0.70710678118654752f));
}
// XOR swizzle: row-major [row][BK] bf16 tile -> conflict-free ds_read_b128 (G4).
__device__ __forceinline__ int swz(int row, int k) {
  return row * BK + (k ^ ((row & 7) << 3));
}
// async global->LDS, 16B per lane. LDS dest = wave-uniform base + lane*16.
__device__ __forceinline__ void gll16(const void* g, void* l) {
  __builtin_amdgcn_global_load_lds(
      (const __attribute__((address_space(1))) void*)g,
      (__attribute__((address_space(3))) void*)l, 16, 0, 0);
}

// ---- kernel 1: deterministic expert routing (ballot rank) + tile list ----
__global__ __launch_bounds__(1024) void route_kernel(
    const int* __restrict__ eidx, int* __restrict__ perm,
    int* __restrict__ tile_e, int* __restrict__ tile_row,
    int* __restrict__ tile_len, int* __restrict__ ntiles) {
  __shared__ int wcnt[16][E_NUM];
  __shared__ int wpre[16][E_NUM];
  __shared__ int offsh[E_NUM + 1];
  const int t = threadIdx.x;        // 1024
  const int lane = t & 63, wave = t >> 6;
  const int e = eidx[t];
  unsigned long long myMask = 0;
#pragma unroll
  for (int ee = 0; ee < E_NUM; ++ee) {
    unsigned long long m = __ballot(e == ee);
    if (ee == e) myMask = m;
    if (lane == 0) wcnt[wave][ee] = __popcll(m);
  }
  const int rank = __popcll(myMask & ((1ull << lane) - 1ull));
  __syncthreads();
  if (t < 16 * E_NUM) {
    const int w = t >> 3, ee = t & 7;
    int p = 0;
    for (int w2 = 0; w2 < w; ++w2) p += wcnt[w2][ee];
    wpre[w][ee] = p;
  }
  __syncthreads();
  if (t <= E_NUM) {
    int off = 0;
    for (int ee = 0; ee < t; ++ee) off += wpre[15][ee] + wcnt[15][ee];
    offsh[t] = off;
  }
  __syncthreads();
  perm[offsh[e] + wpre[wave][e] + rank] = t;
  if (t == 0) {
    int n = 0;
    for (int ee = 0; ee < E_NUM; ++ee)
      for (int r = offsh[ee]; r < offsh[ee + 1]; r += BM) {
        tile_e[n] = ee; tile_row[n] = r;
        tile_len[n] = min(offsh[ee + 1] - r, BM); ++n;
      }
    *ntiles = n;
    for (int i = n; i < MSLOTS; ++i) { tile_e[i] = 0; tile_row[i] = 0; tile_len[i] = 0; }
  }
}

// ---- kernel 2: gather x into perm order, f32 -> bf16 ----
__global__ void gather_kernel(const float* __restrict__ x,
                              const int* __restrict__ perm,
                              unsigned short* __restrict__ xg) {
  const int idx = blockIdx.x * 256 + threadIdx.x;
  if (idx >= T_TOK * (H_DIM / 8)) return;
  const int p = idx / (H_DIM / 8);
  const int c = (idx % (H_DIM / 8)) * 8;
  const int t = perm[p];
  const float* src = x + (size_t)t * H_DIM + c;
  const float4 v0 = *(const float4*)(src);
  const float4 v1 = *(const float4*)(src + 4);
  short8 o;
  o[0] = (short)f2bf(v0.x); o[1] = (short)f2bf(v0.y);
  o[2] = (short)f2bf(v0.z); o[3] = (short)f2bf(v0.w);
  o[4] = (short)f2bf(v1.x); o[5] = (short)f2bf(v1.y);
  o[6] = (short)f2bf(v1.z); o[7] = (short)f2bf(v1.w);
  *(short8*)(xg + (size_t)p * H_DIM + c) = o;
}

// ---- grouped GEMM, BM=128 x BN=64, 8 waves (4x2, 32x32 each), dbuf LDS ----
// T4 counted-vmcnt pipeline: steady-state vmcnt(8) keeps the next B-tile's 8
// coalesced loads in flight across the barrier; vmcnt(0) only in last phase.
// A via global_load_lds (pre-swizzled source, linear dest, m173).
// B: lane = column -> 8x coalesced dword loads, one ds_write_b128.
template <int N_FULL, int K_FULL, int KLOOP, bool IS_FFN1>
__global__ __launch_bounds__(512, 4) void moe_gemm(
    const unsigned short* __restrict__ A,   // [T_TOK][K_FULL] bf16 (perm order)
    const float* __restrict__ W,            // [E][K_FULL][N_FULL] f32
    const float* __restrict__ bias,         // [E][N_FULL] (FFN1 only)
    const int* __restrict__ tile_e, const int* __restrict__ tile_row,
    const int* __restrict__ tile_len, const int* __restrict__ ntiles,
    unsigned short* __restrict__ out_bf,    // FFN1 out
    float* __restrict__ part) {             // FFN2 partials [KSPLIT2][T_TOK][N_FULL]
  constexpr int KT = KLOOP / BK;            // 12 (even)
  const int tid  = threadIdx.x;
  const int slot = blockIdx.y;
  if (slot >= *ntiles) return;
  const int e    = tile_e[slot];
  const int row0 = tile_row[slot];
  const int len  = tile_len[slot];
  const int n0   = blockIdx.x * BN;
  const int kbase = blockIdx.z * KLOOP;
  const float* We = W + (size_t)e * K_FULL * N_FULL;

  __shared__ unsigned short As[2][BM * BK];   // 2 x 16 KB, linear chunk order
  __shared__ unsigned short Bs[2][BN * BK];   // 2 x  8 KB, [n][k] swizzled

  const int lane = tid & 63;
  const int wave = tid >> 6;
  const int wm = wave >> 1, wn = wave & 1;    // 4x2 waves: 32 rows x 32 cols each
  const int lr = lane & 15;
  const int lk = (lane >> 4) * 8;

  // A gll addressing: linear LDS chunk c holds global (r, kc ^ xor(r)) so the
  // swizzled ds_read below sees the standard layout (pre-swizzled source).
  const unsigned short* agsrc[2];
  int aoff[2];
#pragma unroll
  for (int i = 0; i < 2; ++i) {
    const int c = tid + i * 512;
    const int r = c >> 3, kc = (c & 7) << 3;
    int grow = row0 + r; grow = grow < T_TOK ? grow : (T_TOK - 1);
    agsrc[i] = A + (size_t)grow * K_FULL + kbase + (kc ^ ((r & 7) << 3));
    aoff[i]  = ((tid & ~63) + i * 512) * 8;   // wave-uniform 16B-chunk base
  }
  // B staging: lane = column (coalesced 256B/instr), wave owns 8 k-rows.
  const int bn_ = tid & 63;                   // col
  const int kb8 = (tid >> 6) * 8;             // row block
  const float* wpB = We + (size_t)(kbase + kb8) * N_FULL + n0 + bn_;

  f32x4 acc[2][2] = {};
  float X[8], Y[8];

  auto issueA = [&](int kt, int buf) {
#pragma unroll
    for (int i = 0; i < 2; ++i)
      gll16(agsrc[i] + kt * BK, &As[buf][aoff[i]]);
  };
  auto loadB = [&](int kt, float* d) {
#pragma unroll
    for (int j = 0; j < 8; ++j)
      d[j] = wpB[(size_t)(kt * BK + j) * N_FULL];   // coalesced across lanes
  };
  auto writeB = [&](int buf, const float* d) {
    short8 p;
#pragma unroll
    for (int j = 0; j < 8; ++j) p[j] = (short)f2bf(d[j]);
    *(short8*)(&Bs[buf][swz(bn_, kb8)]) = p;        // one b128
  };
  auto mfma_tile = [&](int buf) {
#pragma unroll
    for (int ks = 0; ks < 2; ++ks) {
      const int kp = ks * 32 + lk;
      short8 af[2], bfr[2];
#pragma unroll
      for (int m = 0; m < 2; ++m)
        af[m] = *(const short8*)(&As[buf][swz(wm * 32 + m * 16 + lr, kp)]);
#pragma unroll
      for (int n = 0; n < 2; ++n)
        bfr[n] = *(const short8*)(&Bs[buf][swz(wn * 32 + n * 16 + lr, kp)]);
#pragma unroll
      for (int m = 0; m < 2; ++m)
#pragma unroll
        for (int n = 0; n < 2; ++n)
          acc[m][n] = __builtin_amdgcn_mfma_f32_16x16x32_bf16(af[m], bfr[n], acc[m][n], 0, 0, 0);
    }
  };
  // phase t entry queue (oldest->newest): B(t) x8, A(t) x2, B(t+1) x8.
  // vmcnt(8) drains B(t)+A(t), keeps B(t+1) in flight across the barrier.
  auto phase = [&](int t, int buf, float* setCur, bool nextA, bool nextB, bool drain) {
    if (drain) asm volatile("s_waitcnt vmcnt(0)" ::: "memory");
    else       asm volatile("s_waitcnt vmcnt(8)" ::: "memory");
    writeB(buf, setCur);
    asm volatile("s_waitcnt lgkmcnt(0)" ::: "memory");
    __builtin_amdgcn_s_barrier();
    __builtin_amdgcn_sched_barrier(0);
    if (nextA) issueA(t + 1, buf ^ 1);
    __builtin_amdgcn_sched_barrier(0);
    if (nextB) loadB(t + 2, setCur);     // reuses the set just written to LDS
    __builtin_amdgcn_sched_barrier(0);
    mfma_tile(buf);
  };

  loadB(0, X);
  __builtin_amdgcn_sched_barrier(0);
  issueA(0, 0);
  __builtin_amdgcn_sched_barrier(0);
  loadB(1, Y);
#pragma unroll 1
  for (int t = 0; t < KT - 2; t += 2) {
    phase(t,     0, X, true, true, false);
    phase(t + 1, 1, Y, true, true, false);
  }
  phase(KT - 2, 0, X, true,  false, false);
  phase(KT - 1, 1, Y, false, false, true);

  // epilogue: C/D layout col=lane&15, row=(lane>>4)*4+j  [verified m89]
#pragma unroll
  for (int n = 0; n < 2; ++n) {
    const int gc = n0 + wn * 32 + n * 16 + lr;
    float bv = 0.f;
    if constexpr (IS_FFN1) bv = bias[(size_t)e * N_FULL + gc];
#pragma unroll
    for (int m = 0; m < 2; ++m) {
      const int rbase = wm * 32 + m * 16 + (lane >> 4) * 4;
#pragma unroll
      for (int j = 0; j < 4; ++j) {
        const int rl = rbase + j;
        if (rl < len) {
          if constexpr (IS_FFN1) {
            out_bf[(size_t)(row0 + rl) * N_FULL + gc] = f2bf(gelu_exact(acc[m][n][j] + bv));
          } else {
            part[((size_t)blockIdx.z * T_TOK + row0 + rl) * N_FULL + gc] = acc[m][n][j];
          }
        }
      }
    }
  }
}

// ---- kernel 5: split-K sum + bias2 + residual + LayerNorm ----
__global__ void ln_kernel(const float* __restrict__ part,
                          const float* __restrict__ x,
                          const int* __restrict__ perm,
                          const int* __restrict__ eidx,
                          const float* __restrict__ b2,
                          const float* __restrict__ gamma,
                          const float* __restrict__ beta,
                          float* __restrict__ out) {
  const int p = blockIdx.x;
  const int tid = threadIdx.x;  // 256
  const int t = perm[p];
  const int e = eidx[t];
  float v[3], s = 0.f, ss = 0.f;
#pragma unroll
  for (int i = 0; i < 3; ++i) {
    const int c = tid + i * 256;
    float a = x[(size_t)t * H_DIM + c] + b2[(size_t)e * H_DIM + c];
#pragma unroll
    for (int s4 = 0; s4 < KSPLIT2; ++s4)
      a += part[((size_t)s4 * T_TOK + p) * H_DIM + c];
    v[i] = a; s += a; ss += a * a;
  }
#pragma unroll
  for (int o = 32; o; o >>= 1) { s += __shfl_down(s, o); ss += __shfl_down(ss, o); }
  __shared__ float ps[4], pss[4];
  __shared__ float mu_s, ir_s;
  const int w = tid >> 6;
  if ((tid & 63) == 0) { ps[w] = s; pss[w] = ss; }
  __syncthreads();
  if (tid == 0) {
    const float S = ps[0] + ps[1] + ps[2] + ps[3];
    const float SS = pss[0] + pss[1] + pss[2] + pss[3];
    const float mu = S * (1.0f / H_DIM);
    const float var = SS * (1.0f / H_DIM) - mu * mu;
    mu_s = mu; ir_s = rsqrtf(var + 1e-12f);
  }
  __syncthreads();
  const float mu = mu_s, ir = ir_s;
#pragma unroll
  for (int i = 0; i < 3; ++i) {
    const int c = tid + i * 256;
    out[(size_t)t * H_DIM + c] = (v[i] - mu) * ir * gamma[c] + beta[c];
  }
}

extern "C" void kernel_launch(void* const* d_in, const int* in_sizes, int n_in,
                              void* d_out, int out_size, void* d_ws, size_t ws_size,
                              hipStream_t stream) {
  const float* x     = (const float*)d_in[0];
  const int*   eidx  = (const int*)d_in[1];
  const float* W1    = (const float*)d_in[2];
  const float* b1    = (const float*)d_in[3];
  const float* W2    = (const float*)d_in[4];
  const float* b2    = (const float*)d_in[5];
  const float* gamma = (const float*)d_in[6];
  const float* beta  = (const float*)d_in[7];
  float* out = (float*)d_out;

  char* ws = (char*)d_ws;
  int* perm     = (int*)(ws);
  int* tile_e   = (int*)(ws + 4096);
  int* tile_row = (int*)(ws + 4352);
  int* tile_len = (int*)(ws + 4608);
  int* ntiles   = (int*)(ws + 4864);
  size_t off = 8192;
  unsigned short* xg = (unsigned short*)(ws + off);  off += (size_t)2 * T_TOK * H_DIM;   // 1.5 MB
  unsigned short* inter = (unsigned short*)(ws + off); off += (size_t)2 * T_TOK * I_DIM; // 6 MB
  float* part = (float*)(ws + off);                                                      // 12 MB

  route_kernel<<<1, T_TOK, 0, stream>>>(eidx, perm, tile_e, tile_row, tile_len, ntiles);
  gather_kernel<<<(T_TOK * (H_DIM / 8) + 255) / 256, 256, 0, stream>>>(x, perm, xg);
  // FFN1: N=3072, K=768. grid 48 x 16
  moe_gemm<I_DIM, H_DIM, H_DIM, true>
      <<<dim3(I_DIM / BN, MSLOTS, 1), 512, 0, stream>>>(
      xg, W1, b1, tile_e, tile_row, tile_len, ntiles, inter, nullptr);
  // FFN2: N=768, K=3072 split 4 x 768. grid 12 x 16 x 4
  moe_gemm<H_DIM, I_DIM, I_DIM / KSPLIT2, false>
      <<<dim3(H_DIM / BN, MSLOTS, KSPLIT2), 512, 0, stream>>>(
      inter, W2, nullptr, tile_e, tile_row, tile_len, ntiles, nullptr, part);
  ln_kernel<<<T_TOK, 256, 0, stream>>>(part, x, perm, eidx, b2, gamma, beta, out);
  (void)in_sizes; (void)n_in; (void)out_size; (void)ws_size;
}